// Round 1
// baseline (3704.062 us; speedup 1.0000x reference)
//
#include <hip/hip_runtime.h>
#include <hip/hip_bf16.h>
#include <cstdint>

#define Bsz   4
#define Ssz   512
#define HIDsz 4096
#define NHsz  32
#define NKVsz 8
#define Dsz   128
#define CAPsz 2048
#define EPSf  1e-6f
#define QK_SCALEf 0.08838834764831845f  // 1/sqrt(128)

// ============================================================================
// GEMM f32: C(MxN) = A(MxK) @ B(KxN), row-major. Tile 128x128, K-tile 16.
// MODE 0: plain row-major write. MODE 1: scatter into (B,NKV,CAP,D) cache at
// row pos = start_idx[b] + s.
// ============================================================================
template<int MODE>
__global__ __launch_bounds__(256) void gemm_f32_kernel(
    const float* __restrict__ A, const float* __restrict__ Bw,
    float* __restrict__ C, int M, int N, int K,
    const int* __restrict__ start_idx)
{
    __shared__ float As[16][132];   // transposed: As[k][m], pad keeps banks spread
    __shared__ float Bs[16][132];   // Bs[k][n]
    const int t  = threadIdx.x;
    const int tx = t & 15, ty = t >> 4;
    const int m0 = blockIdx.y * 128, n0 = blockIdx.x * 128;

    float acc[8][8];
#pragma unroll
    for (int r = 0; r < 8; r++)
#pragma unroll
        for (int c = 0; c < 8; c++) acc[r][c] = 0.f;

    for (int k0 = 0; k0 < K; k0 += 16) {
        // A tile: 128 rows x 16 k, float4 along k, store transposed (2-way max)
#pragma unroll
        for (int i = 0; i < 2; i++) {
            int p = t + i * 256;               // 0..511
            int row = p >> 2, k4 = (p & 3) * 4;
            float4 av = *(const float4*)(A + (size_t)(m0 + row) * K + k0 + k4);
            As[k4 + 0][row] = av.x;
            As[k4 + 1][row] = av.y;
            As[k4 + 2][row] = av.z;
            As[k4 + 3][row] = av.w;
        }
        // B tile: 16 k x 128 n, float4 along n
#pragma unroll
        for (int i = 0; i < 2; i++) {
            int p = t + i * 256;
            int kr = p >> 5, n4 = (p & 31) * 4;
            *(float4*)&Bs[kr][n4] = *(const float4*)(Bw + (size_t)(k0 + kr) * N + n0 + n4);
        }
        __syncthreads();
#pragma unroll
        for (int kk = 0; kk < 16; kk++) {
            float4 a0 = *(const float4*)&As[kk][ty * 4];
            float4 a1 = *(const float4*)&As[kk][64 + ty * 4];
            float4 b0 = *(const float4*)&Bs[kk][tx * 4];
            float4 b1 = *(const float4*)&Bs[kk][64 + tx * 4];
            float a[8] = {a0.x, a0.y, a0.z, a0.w, a1.x, a1.y, a1.z, a1.w};
            float b[8] = {b0.x, b0.y, b0.z, b0.w, b1.x, b1.y, b1.z, b1.w};
#pragma unroll
            for (int r = 0; r < 8; r++)
#pragma unroll
                for (int c = 0; c < 8; c++) acc[r][c] += a[r] * b[c];
        }
        __syncthreads();
    }

#pragma unroll
    for (int half = 0; half < 2; half++) {
#pragma unroll
        for (int r = 0; r < 4; r++) {
            int rr  = half * 4 + r;
            int row = m0 + half * 64 + ty * 4 + r;
            float4 v0 = make_float4(acc[rr][0], acc[rr][1], acc[rr][2], acc[rr][3]);
            float4 v1 = make_float4(acc[rr][4], acc[rr][5], acc[rr][6], acc[rr][7]);
            if (MODE == 0) {
                *(float4*)(C + (size_t)row * N + n0 + tx * 4)      = v0;
                *(float4*)(C + (size_t)row * N + n0 + 64 + tx * 4) = v1;
            } else {
                int b = row >> 9, s = row & (Ssz - 1);
                int pos = start_idx[b] + s;
                int kv  = n0 >> 7;   // 128-wide tile == one kv head
                float* dst = C + ((size_t)(b * NKVsz + kv) * CAPsz + pos) * Dsz;
                *(float4*)(dst + tx * 4)      = v0;
                *(float4*)(dst + 64 + tx * 4) = v1;
            }
        }
    }
}

// ============================================================================
// RMSNorm + RoPE, one wave per (token, head) row of 128. In-place.
// mode 0: X is (2048, nheads*128) row-major (q_ws)
// mode 1: X is (B, nheads, CAP, D) cache; operates on row pos=start+s
// ============================================================================
__global__ __launch_bounds__(256) void rmsnorm_rope_kernel(
    float* __restrict__ X, const float* __restrict__ w,
    const float* __restrict__ rope, const int* __restrict__ start_idx,
    int nheads, int mode)
{
    int gid   = blockIdx.x * blockDim.x + threadIdx.x;
    int wid   = gid >> 6;
    int lane  = threadIdx.x & 63;
    int token = wid / nheads;
    int h     = wid - token * nheads;
    int b = token >> 9, s = token & (Ssz - 1);
    int pos = start_idx[b] + s;
    float* row;
    if (mode == 0) row = X + (size_t)token * (nheads * Dsz) + h * Dsz;
    else           row = X + ((size_t)(b * nheads + h) * CAPsz + pos) * Dsz;

    float x1 = row[lane], x2 = row[lane + 64];
    float ss = x1 * x1 + x2 * x2;
#pragma unroll
    for (int off = 32; off > 0; off >>= 1) ss += __shfl_xor(ss, off);
    float rn  = rsqrtf(ss * (1.f / 128.f) + EPSf);
    float xn1 = x1 * rn * w[lane];
    float xn2 = x2 * rn * w[lane + 64];
    float c   = rope[(size_t)pos * Dsz + lane];        // cos (batch 0 slice)
    float sn  = rope[(size_t)pos * Dsz + 64 + lane];   // sin
    row[lane]      = xn1 * c - xn2 * sn;
    row[lane + 64] = xn2 * c + xn1 * sn;
}

// ============================================================================
// Flash attention. Block = (q_tile of 64, head, batch). 256 threads.
// Q staged bf16 (pre-scaled), K/V share one f32 transposed LDS buffer,
// P staged bf16, online softmax, O in registers (4 rows x 8 cols / thread).
// ============================================================================
__global__ __launch_bounds__(256) void attn_kernel(
    const float* __restrict__ Q, const float* __restrict__ Kc,
    const float* __restrict__ Vc, float* __restrict__ O,
    const int* __restrict__ start_idx)
{
    __shared__ unsigned short Qs[128][68];   // [d][i], bf16, scaled
    __shared__ float          KVs[128][65];  // [d][j] transposed, K then V
    __shared__ unsigned short Ps[64][68];    // [j][i], bf16

    const int t  = threadIdx.x;
    const int tx = t & 15, ty = t >> 4;
    const int qt = blockIdx.x, h = blockIdx.y, b = blockIdx.z;
    const int s0 = qt * 64;
    const int kv = h >> 2;                   // GQA group of 4
    const int start = start_idx[b];

    // ---- load Q tile (64 x 128), scale, store transposed bf16 ----
    const float* qbase = Q + ((size_t)(b * Ssz + s0)) * (NHsz * Dsz) + h * Dsz;
#pragma unroll
    for (int i = 0; i < 8; i++) {
        int p = t + i * 256;                 // 0..2047
        int row = p >> 5, d4 = (p & 31) * 4;
        float4 v = *(const float4*)(qbase + (size_t)row * (NHsz * Dsz) + d4);
        Qs[d4 + 0][row] = (unsigned short)((__float_as_uint(v.x * QK_SCALEf) + 0x8000u) >> 16);
        Qs[d4 + 1][row] = (unsigned short)((__float_as_uint(v.y * QK_SCALEf) + 0x8000u) >> 16);
        Qs[d4 + 2][row] = (unsigned short)((__float_as_uint(v.z * QK_SCALEf) + 0x8000u) >> 16);
        Qs[d4 + 3][row] = (unsigned short)((__float_as_uint(v.w * QK_SCALEf) + 0x8000u) >> 16);
    }

    float m_run[4], l_run[4], Oa[4][8];
#pragma unroll
    for (int r = 0; r < 4; r++) {
        m_run[r] = -1e30f; l_run[r] = 0.f;
#pragma unroll
        for (int c = 0; c < 8; c++) Oa[r][c] = 0.f;
    }

    const float* kbase = Kc + (size_t)(b * NKVsz + kv) * CAPsz * Dsz;
    const float* vbase = Vc + (size_t)(b * NKVsz + kv) * CAPsz * Dsz;

    int t_hi = start + s0 + 63;
    if (t_hi > CAPsz - 1) t_hi = CAPsz - 1;

    for (int t0 = 0; t0 <= t_hi; t0 += 64) {
        __syncthreads();                     // KVs free (prev PV done); Qs visible
        // ---- K tile -> KVs transposed ----
#pragma unroll
        for (int i = 0; i < 8; i++) {
            int p = t + i * 256;
            int j = p >> 5, d4 = (p & 31) * 4;
            float4 v = *(const float4*)(kbase + (size_t)(t0 + j) * Dsz + d4);
            KVs[d4 + 0][j] = v.x; KVs[d4 + 1][j] = v.y;
            KVs[d4 + 2][j] = v.z; KVs[d4 + 3][j] = v.w;
        }
        __syncthreads();

        // ---- scores S[4][4]: rows ty*4+r, cols tx*4+c ----
        float Sc[4][4];
#pragma unroll
        for (int r = 0; r < 4; r++)
#pragma unroll
            for (int c = 0; c < 4; c++) Sc[r][c] = 0.f;

#pragma unroll 8
        for (int d = 0; d < 128; d++) {
            uint2 qa = *(const uint2*)&Qs[d][ty * 4];
            float a0 = __uint_as_float(qa.x << 16);
            float a1 = __uint_as_float(qa.x & 0xffff0000u);
            float a2 = __uint_as_float(qa.y << 16);
            float a3 = __uint_as_float(qa.y & 0xffff0000u);
            float b0 = KVs[d][tx * 4 + 0];
            float b1 = KVs[d][tx * 4 + 1];
            float b2 = KVs[d][tx * 4 + 2];
            float b3 = KVs[d][tx * 4 + 3];
            Sc[0][0] += a0 * b0; Sc[0][1] += a0 * b1; Sc[0][2] += a0 * b2; Sc[0][3] += a0 * b3;
            Sc[1][0] += a1 * b0; Sc[1][1] += a1 * b1; Sc[1][2] += a1 * b2; Sc[1][3] += a1 * b3;
            Sc[2][0] += a2 * b0; Sc[2][1] += a2 * b1; Sc[2][2] += a2 * b2; Sc[2][3] += a2 * b3;
            Sc[3][0] += a3 * b0; Sc[3][1] += a3 * b1; Sc[3][2] += a3 * b2; Sc[3][3] += a3 * b3;
        }

        // ---- mask + online softmax (row stats across tx = 16 lanes) ----
#pragma unroll
        for (int r = 0; r < 4; r++) {
            int pos_row = start + s0 + ty * 4 + r;
            float mrow = -1e30f;
#pragma unroll
            for (int c = 0; c < 4; c++) {
                int col = t0 + tx * 4 + c;
                if (col > pos_row) Sc[r][c] = -1e30f;
                mrow = fmaxf(mrow, Sc[r][c]);
            }
#pragma unroll
            for (int off = 1; off < 16; off <<= 1) mrow = fmaxf(mrow, __shfl_xor(mrow, off));
            float m_new = fmaxf(m_run[r], mrow);
            float alpha = __expf(m_run[r] - m_new);
            float psum = 0.f;
#pragma unroll
            for (int c = 0; c < 4; c++) {
                float p = __expf(Sc[r][c] - m_new);
                Sc[r][c] = p;
                psum += p;
            }
#pragma unroll
            for (int off = 1; off < 16; off <<= 1) psum += __shfl_xor(psum, off);
            l_run[r] = l_run[r] * alpha + psum;
            m_run[r] = m_new;
#pragma unroll
            for (int c = 0; c < 8; c++) Oa[r][c] *= alpha;
#pragma unroll
            for (int c = 0; c < 4; c++)
                Ps[tx * 4 + c][ty * 4 + r] =
                    (unsigned short)((__float_as_uint(Sc[r][c]) + 0x8000u) >> 16);
        }
        __syncthreads();                     // Ps written, K reads done

        // ---- V tile -> KVs transposed (overwrite K) ----
#pragma unroll
        for (int i = 0; i < 8; i++) {
            int p = t + i * 256;
            int j = p >> 5, d4 = (p & 31) * 4;
            float4 v = *(const float4*)(vbase + (size_t)(t0 + j) * Dsz + d4);
            KVs[d4 + 0][j] = v.x; KVs[d4 + 1][j] = v.y;
            KVs[d4 + 2][j] = v.z; KVs[d4 + 3][j] = v.w;
        }
        __syncthreads();

        // ---- PV: O[r][cc] += P[r] * V, cols d = tx*4+c and 64+tx*4+c ----
#pragma unroll 4
        for (int j = 0; j < 64; j++) {
            uint2 pr = *(const uint2*)&Ps[j][ty * 4];
            float p0 = __uint_as_float(pr.x << 16);
            float p1 = __uint_as_float(pr.x & 0xffff0000u);
            float p2 = __uint_as_float(pr.y << 16);
            float p3 = __uint_as_float(pr.y & 0xffff0000u);
            float v0 = KVs[tx * 4 + 0][j];
            float v1 = KVs[tx * 4 + 1][j];
            float v2 = KVs[tx * 4 + 2][j];
            float v3 = KVs[tx * 4 + 3][j];
            float v4 = KVs[64 + tx * 4 + 0][j];
            float v5 = KVs[64 + tx * 4 + 1][j];
            float v6 = KVs[64 + tx * 4 + 2][j];
            float v7 = KVs[64 + tx * 4 + 3][j];
            Oa[0][0] += p0 * v0; Oa[0][1] += p0 * v1; Oa[0][2] += p0 * v2; Oa[0][3] += p0 * v3;
            Oa[0][4] += p0 * v4; Oa[0][5] += p0 * v5; Oa[0][6] += p0 * v6; Oa[0][7] += p0 * v7;
            Oa[1][0] += p1 * v0; Oa[1][1] += p1 * v1; Oa[1][2] += p1 * v2; Oa[1][3] += p1 * v3;
            Oa[1][4] += p1 * v4; Oa[1][5] += p1 * v5; Oa[1][6] += p1 * v6; Oa[1][7] += p1 * v7;
            Oa[2][0] += p2 * v0; Oa[2][1] += p2 * v1; Oa[2][2] += p2 * v2; Oa[2][3] += p2 * v3;
            Oa[2][4] += p2 * v4; Oa[2][5] += p2 * v5; Oa[2][6] += p2 * v6; Oa[2][7] += p2 * v7;
            Oa[3][0] += p3 * v0; Oa[3][1] += p3 * v1; Oa[3][2] += p3 * v2; Oa[3][3] += p3 * v3;
            Oa[3][4] += p3 * v4; Oa[3][5] += p3 * v5; Oa[3][6] += p3 * v6; Oa[3][7] += p3 * v7;
        }
    }

    // ---- epilogue: O / l -> attn_ws (token-major, h*128+d) ----
    float* obase = O + ((size_t)(b * Ssz + s0)) * (NHsz * Dsz) + h * Dsz;
#pragma unroll
    for (int r = 0; r < 4; r++) {
        float inv = 1.f / l_run[r];
        float4 v0 = make_float4(Oa[r][0] * inv, Oa[r][1] * inv, Oa[r][2] * inv, Oa[r][3] * inv);
        float4 v1 = make_float4(Oa[r][4] * inv, Oa[r][5] * inv, Oa[r][6] * inv, Oa[r][7] * inv);
        *(float4*)(obase + (size_t)(ty * 4 + r) * (NHsz * Dsz) + tx * 4)      = v0;
        *(float4*)(obase + (size_t)(ty * 4 + r) * (NHsz * Dsz) + 64 + tx * 4) = v1;
    }
}

// ============================================================================
extern "C" void kernel_launch(void* const* d_in, const int* in_sizes, int n_in,
                              void* d_out, int out_size, void* d_ws, size_t ws_size,
                              hipStream_t stream) {
    (void)in_sizes; (void)n_in; (void)out_size; (void)ws_size;
    const float* hidden    = (const float*)d_in[0];
    const float* k_cache   = (const float*)d_in[1];
    const float* v_cache   = (const float*)d_in[2];
    const float* rope      = (const float*)d_in[3];
    const int*   start_idx = (const int*)d_in[5];
    const float* Wq        = (const float*)d_in[6];
    const float* Wk        = (const float*)d_in[7];
    const float* Wv        = (const float*)d_in[8];
    const float* Wo        = (const float*)d_in[9];
    const float* q_norm_w  = (const float*)d_in[10];
    const float* k_norm_w  = (const float*)d_in[11];

    float* out   = (float*)d_out;
    float* out_k = out + (size_t)Bsz * Ssz * HIDsz;             // 8388608
    float* out_v = out_k + (size_t)Bsz * NKVsz * CAPsz * Dsz;   // +8388608

    float* q_ws    = (float*)d_ws;                              // 2048 x 4096 f32
    float* attn_ws = q_ws + (size_t)2048 * 4096;                // 2048 x 4096 f32

    const size_t cache_bytes = (size_t)Bsz * NKVsz * CAPsz * Dsz * sizeof(float);
    hipMemcpyAsync(out_k, k_cache, cache_bytes, hipMemcpyDeviceToDevice, stream);
    hipMemcpyAsync(out_v, v_cache, cache_bytes, hipMemcpyDeviceToDevice, stream);

    // QKV projections
    gemm_f32_kernel<0><<<dim3(32, 16), 256, 0, stream>>>(hidden, Wq, q_ws, 2048, 4096, 4096, nullptr);
    gemm_f32_kernel<1><<<dim3(8, 16), 256, 0, stream>>>(hidden, Wk, out_k, 2048, 1024, 4096, start_idx);
    gemm_f32_kernel<1><<<dim3(8, 16), 256, 0, stream>>>(hidden, Wv, out_v, 2048, 1024, 4096, start_idx);

    // RMSNorm + RoPE (q in ws; k in-place on cache slice)
    rmsnorm_rope_kernel<<<16384, 256, 0, stream>>>(q_ws, q_norm_w, rope, start_idx, NHsz, 0);
    rmsnorm_rope_kernel<<<4096, 256, 0, stream>>>(out_k, k_norm_w, rope, start_idx, NKVsz, 1);

    // Attention
    attn_kernel<<<dim3(8, NHsz, Bsz), 256, 0, stream>>>(q_ws, out_k, out_v, attn_ws, start_idx);

    // Output projection
    gemm_f32_kernel<0><<<dim3(32, 16), 256, 0, stream>>>(attn_ws, Wo, out, 2048, 4096, 4096, nullptr);
}

// Round 4
// 1608.285 us; speedup vs baseline: 2.3031x; 2.3031x over previous
//
#include <hip/hip_runtime.h>
#include <hip/hip_bf16.h>
#include <cstdint>

#define Bsz   4
#define Ssz   512
#define HIDsz 4096
#define NHsz  32
#define NKVsz 8
#define Dsz   128
#define CAPsz 2048
#define EPSf  1e-6f
#define QK_SCALEf 0.08838834764831845f  // 1/sqrt(128)

typedef __attribute__((ext_vector_type(8))) short short8;
typedef __attribute__((ext_vector_type(4))) float f32x4;

__device__ __forceinline__ unsigned short f2bf(float x) {
    unsigned u = __float_as_uint(x);
    return (unsigned short)((u + 0x7fffu + ((u >> 16) & 1u)) >> 16);
}

// async 16B global->LDS; lds base must be WAVE-UNIFORM (HW adds lane*16)
__device__ __forceinline__ void gload16(const void* g, void* l) {
    __builtin_amdgcn_global_load_lds(
        (const __attribute__((address_space(1))) unsigned int*)g,
        (__attribute__((address_space(3))) unsigned int*)l, 16, 0, 0);
}

// ============================================================================
// f32 -> bf16 flat convert (vectorized float4 -> ushort4)
// ============================================================================
__global__ __launch_bounds__(256) void convert_bf16_kernel(
    const float* __restrict__ in, unsigned short* __restrict__ out, int n4)
{
    int i = blockIdx.x * blockDim.x + threadIdx.x;
    if (i < n4) {
        float4 v = ((const float4*)in)[i];
        ushort4 o;
        o.x = f2bf(v.x); o.y = f2bf(v.y); o.z = f2bf(v.z); o.w = f2bf(v.w);
        ((ushort4*)out)[i] = o;
    }
}

// ============================================================================
// W (K x N, f32 row-major) -> Wt (N x K, bf16 row-major). 64x64 tiles.
// ============================================================================
__global__ __launch_bounds__(256) void transpose_bf16_kernel(
    const float* __restrict__ W, unsigned short* __restrict__ Wt, int K, int N)
{
    __shared__ float tile[64][65];
    const int k0 = blockIdx.y * 64, n0 = blockIdx.x * 64;
    const int t = threadIdx.x;
    const int tr = t >> 4, tc4 = (t & 15) * 4;
#pragma unroll
    for (int i = 0; i < 4; i++) {
        int r = tr + i * 16;
        float4 v = *(const float4*)(W + (size_t)(k0 + r) * N + n0 + tc4);
        tile[r][tc4 + 0] = v.x; tile[r][tc4 + 1] = v.y;
        tile[r][tc4 + 2] = v.z; tile[r][tc4 + 3] = v.w;
    }
    __syncthreads();
#pragma unroll
    for (int i = 0; i < 4; i++) {
        int nr = tr + i * 16;
        ushort4 o;
        o.x = f2bf(tile[tc4 + 0][nr]);
        o.y = f2bf(tile[tc4 + 1][nr]);
        o.z = f2bf(tile[tc4 + 2][nr]);
        o.w = f2bf(tile[tc4 + 3][nr]);
        *(ushort4*)(Wt + (size_t)(n0 + nr) * K + k0 + tc4) = o;
    }
}

// ============================================================================
// bf16 MFMA GEMM (m97 structure): C(MxN,f32) = A(MxK,bf16) @ Bt(NxK,bf16)^T
// 128x128 tile, BK=64, 4 waves each computing 64x64 via 4x4 of 16x16x32 MFMA.
// Staging: one gload16 = 64 lanes x 16B = 8 rows of 64 bf16; 16 chunks of
// 8 rows cover the 128-row tile (i*4+wv over 0..15). NO second pass.
// MODE 0: plain row-major f32 write. MODE 1: scatter rows into (B,NKV,CAP,D)
// cache at pos = start_idx[b] + s.
// ============================================================================
template<int MODE>
__global__ __launch_bounds__(256, 2) void gemm_bf16_kernel(
    const unsigned short* __restrict__ A,   // M x K
    const unsigned short* __restrict__ Bt,  // N x K
    float* __restrict__ C, int M, int N, int K,
    const int* __restrict__ start_idx)
{
    __shared__ __align__(16) unsigned short As[128 * 64];
    __shared__ __align__(16) unsigned short Bs[128 * 64];
    const int t    = threadIdx.x;
    const int lane = t & 63, wv = t >> 6;
    const int m0 = blockIdx.y * 128, n0 = blockIdx.x * 128;
    const int rw = (wv & 1) * 64, cw = (wv >> 1) * 64;

    f32x4 acc[4][4];
#pragma unroll
    for (int r = 0; r < 4; r++)
#pragma unroll
        for (int c = 0; c < 4; c++) acc[r][c] = (f32x4){0.f, 0.f, 0.f, 0.f};

    const int arow = lane >> 3;          // 0..7  row within 8-row chunk
    const int acol = (lane & 7) * 8;     // k offset in elements (8 bf16 = 16 B)
    const int fr = lane & 15, fq = (lane >> 4) * 8;

    for (int k0 = 0; k0 < K; k0 += 64) {
        __syncthreads();
#pragma unroll
        for (int i = 0; i < 4; i++) {
            int ro = (i * 4 + wv) * 8;   // 16 chunks x 8 rows = 128 rows total
            gload16(A  + (size_t)(m0 + ro + arow) * K + k0 + acol, As + (size_t)ro * 64);
            gload16(Bt + (size_t)(n0 + ro + arow) * K + k0 + acol, Bs + (size_t)ro * 64);
        }
        __syncthreads();
#pragma unroll
        for (int kk = 0; kk < 2; kk++) {
            short8 af[4], bfr[4];
#pragma unroll
            for (int r = 0; r < 4; r++)
                af[r] = *(const short8*)&As[(rw + r * 16 + fr) * 64 + kk * 32 + fq];
#pragma unroll
            for (int c = 0; c < 4; c++)
                bfr[c] = *(const short8*)&Bs[(cw + c * 16 + fr) * 64 + kk * 32 + fq];
#pragma unroll
            for (int r = 0; r < 4; r++)
#pragma unroll
                for (int c = 0; c < 4; c++)
                    acc[r][c] = __builtin_amdgcn_mfma_f32_16x16x32_bf16(
                        af[r], bfr[c], acc[r][c], 0, 0, 0);
        }
    }

    // epilogue: C/D layout col=lane&15, row=(lane>>4)*4+reg
    int pos0 = 0;
    if (MODE == 1) pos0 = start_idx[m0 >> 9];   // 128-row tile never crosses batch
#pragma unroll
    for (int r = 0; r < 4; r++) {
#pragma unroll
        for (int c = 0; c < 4; c++) {
            int col = n0 + cw + c * 16 + (lane & 15);
#pragma unroll
            for (int reg = 0; reg < 4; reg++) {
                int row = m0 + rw + r * 16 + (lane >> 4) * 4 + reg;
                float val = acc[r][c][reg];
                if (MODE == 0) {
                    C[(size_t)row * N + col] = val;
                } else {
                    int pos = pos0 + (row & (Ssz - 1));
                    int kv = col >> 7, d = col & 127;
                    int b = row >> 9;
                    C[((size_t)(b * NKVsz + kv) * CAPsz + pos) * Dsz + d] = val;
                }
            }
        }
    }
}

// ============================================================================
// RMSNorm + RoPE, one wave per (token, head) row of 128. In-place f32.
// mode 0: X is (2048, nheads*128) row-major (q_ws)
// mode 1: X is (B, nheads, CAP, D) cache; operates on row pos=start+s
// ============================================================================
__global__ __launch_bounds__(256) void rmsnorm_rope_kernel(
    float* __restrict__ X, const float* __restrict__ w,
    const float* __restrict__ rope, const int* __restrict__ start_idx,
    int nheads, int mode)
{
    int gid   = blockIdx.x * blockDim.x + threadIdx.x;
    int wid   = gid >> 6;
    int lane  = threadIdx.x & 63;
    int token = wid / nheads;
    int h     = wid - token * nheads;
    int b = token >> 9, s = token & (Ssz - 1);
    int pos = start_idx[b] + s;
    float* row;
    if (mode == 0) row = X + (size_t)token * (nheads * Dsz) + h * Dsz;
    else           row = X + ((size_t)(b * nheads + h) * CAPsz + pos) * Dsz;

    float x1 = row[lane], x2 = row[lane + 64];
    float ss = x1 * x1 + x2 * x2;
#pragma unroll
    for (int off = 32; off > 0; off >>= 1) ss += __shfl_xor(ss, off);
    float rn  = rsqrtf(ss * (1.f / 128.f) + EPSf);
    float xn1 = x1 * rn * w[lane];
    float xn2 = x2 * rn * w[lane + 64];
    float c   = rope[(size_t)pos * Dsz + lane];        // cos (batch 0 slice)
    float sn  = rope[(size_t)pos * Dsz + 64 + lane];   // sin
    row[lane]      = xn1 * c - xn2 * sn;
    row[lane + 64] = xn2 * c + xn1 * sn;
}

// ============================================================================
// Flash attention (f32 VALU). Block = (q_tile of 64, head, batch). 256 thr.
// ============================================================================
__global__ __launch_bounds__(256) void attn_kernel(
    const float* __restrict__ Q, const float* __restrict__ Kc,
    const float* __restrict__ Vc, unsigned short* __restrict__ O,
    const int* __restrict__ start_idx)
{
    __shared__ unsigned short Qs[128][68];   // [d][i], bf16, scaled
    __shared__ float          KVs[128][65];  // [d][j] transposed, K then V
    __shared__ unsigned short Ps[64][68];    // [j][i], bf16

    const int t  = threadIdx.x;
    const int tx = t & 15, ty = t >> 4;
    const int qt = blockIdx.x, h = blockIdx.y, b = blockIdx.z;
    const int s0 = qt * 64;
    const int kv = h >> 2;                   // GQA group of 4
    const int start = start_idx[b];

    const float* qbase = Q + ((size_t)(b * Ssz + s0)) * (NHsz * Dsz) + h * Dsz;
#pragma unroll
    for (int i = 0; i < 8; i++) {
        int p = t + i * 256;                 // 0..2047
        int row = p >> 5, d4 = (p & 31) * 4;
        float4 v = *(const float4*)(qbase + (size_t)row * (NHsz * Dsz) + d4);
        Qs[d4 + 0][row] = (unsigned short)((__float_as_uint(v.x * QK_SCALEf) + 0x8000u) >> 16);
        Qs[d4 + 1][row] = (unsigned short)((__float_as_uint(v.y * QK_SCALEf) + 0x8000u) >> 16);
        Qs[d4 + 2][row] = (unsigned short)((__float_as_uint(v.z * QK_SCALEf) + 0x8000u) >> 16);
        Qs[d4 + 3][row] = (unsigned short)((__float_as_uint(v.w * QK_SCALEf) + 0x8000u) >> 16);
    }

    float m_run[4], l_run[4], Oa[4][8];
#pragma unroll
    for (int r = 0; r < 4; r++) {
        m_run[r] = -1e30f; l_run[r] = 0.f;
#pragma unroll
        for (int c = 0; c < 8; c++) Oa[r][c] = 0.f;
    }

    const float* kbase = Kc + (size_t)(b * NKVsz + kv) * CAPsz * Dsz;
    const float* vbase = Vc + (size_t)(b * NKVsz + kv) * CAPsz * Dsz;

    int t_hi = start + s0 + 63;
    if (t_hi > CAPsz - 1) t_hi = CAPsz - 1;

    for (int t0 = 0; t0 <= t_hi; t0 += 64) {
        __syncthreads();
#pragma unroll
        for (int i = 0; i < 8; i++) {
            int p = t + i * 256;
            int j = p >> 5, d4 = (p & 31) * 4;
            float4 v = *(const float4*)(kbase + (size_t)(t0 + j) * Dsz + d4);
            KVs[d4 + 0][j] = v.x; KVs[d4 + 1][j] = v.y;
            KVs[d4 + 2][j] = v.z; KVs[d4 + 3][j] = v.w;
        }
        __syncthreads();

        float Sc[4][4];
#pragma unroll
        for (int r = 0; r < 4; r++)
#pragma unroll
            for (int c = 0; c < 4; c++) Sc[r][c] = 0.f;

#pragma unroll 8
        for (int d = 0; d < 128; d++) {
            uint2 qa = *(const uint2*)&Qs[d][ty * 4];
            float a0 = __uint_as_float(qa.x << 16);
            float a1 = __uint_as_float(qa.x & 0xffff0000u);
            float a2 = __uint_as_float(qa.y << 16);
            float a3 = __uint_as_float(qa.y & 0xffff0000u);
            float b0 = KVs[d][tx * 4 + 0];
            float b1 = KVs[d][tx * 4 + 1];
            float b2 = KVs[d][tx * 4 + 2];
            float b3 = KVs[d][tx * 4 + 3];
            Sc[0][0] += a0 * b0; Sc[0][1] += a0 * b1; Sc[0][2] += a0 * b2; Sc[0][3] += a0 * b3;
            Sc[1][0] += a1 * b0; Sc[1][1] += a1 * b1; Sc[1][2] += a1 * b2; Sc[1][3] += a1 * b3;
            Sc[2][0] += a2 * b0; Sc[2][1] += a2 * b1; Sc[2][2] += a2 * b2; Sc[2][3] += a2 * b3;
            Sc[3][0] += a3 * b0; Sc[3][1] += a3 * b1; Sc[3][2] += a3 * b2; Sc[3][3] += a3 * b3;
        }

#pragma unroll
        for (int r = 0; r < 4; r++) {
            int pos_row = start + s0 + ty * 4 + r;
            float mrow = -1e30f;
#pragma unroll
            for (int c = 0; c < 4; c++) {
                int col = t0 + tx * 4 + c;
                if (col > pos_row) Sc[r][c] = -1e30f;
                mrow = fmaxf(mrow, Sc[r][c]);
            }
#pragma unroll
            for (int off = 1; off < 16; off <<= 1) mrow = fmaxf(mrow, __shfl_xor(mrow, off));
            float m_new = fmaxf(m_run[r], mrow);
            float alpha = __expf(m_run[r] - m_new);
            float psum = 0.f;
#pragma unroll
            for (int c = 0; c < 4; c++) {
                float p = __expf(Sc[r][c] - m_new);
                Sc[r][c] = p;
                psum += p;
            }
#pragma unroll
            for (int off = 1; off < 16; off <<= 1) psum += __shfl_xor(psum, off);
            l_run[r] = l_run[r] * alpha + psum;
            m_run[r] = m_new;
#pragma unroll
            for (int c = 0; c < 8; c++) Oa[r][c] *= alpha;
#pragma unroll
            for (int c = 0; c < 4; c++)
                Ps[tx * 4 + c][ty * 4 + r] =
                    (unsigned short)((__float_as_uint(Sc[r][c]) + 0x8000u) >> 16);
        }
        __syncthreads();

#pragma unroll
        for (int i = 0; i < 8; i++) {
            int p = t + i * 256;
            int j = p >> 5, d4 = (p & 31) * 4;
            float4 v = *(const float4*)(vbase + (size_t)(t0 + j) * Dsz + d4);
            KVs[d4 + 0][j] = v.x; KVs[d4 + 1][j] = v.y;
            KVs[d4 + 2][j] = v.z; KVs[d4 + 3][j] = v.w;
        }
        __syncthreads();

#pragma unroll 4
        for (int j = 0; j < 64; j++) {
            uint2 pr = *(const uint2*)&Ps[j][ty * 4];
            float p0 = __uint_as_float(pr.x << 16);
            float p1 = __uint_as_float(pr.x & 0xffff0000u);
            float p2 = __uint_as_float(pr.y << 16);
            float p3 = __uint_as_float(pr.y & 0xffff0000u);
            float v0 = KVs[tx * 4 + 0][j];
            float v1 = KVs[tx * 4 + 1][j];
            float v2 = KVs[tx * 4 + 2][j];
            float v3 = KVs[tx * 4 + 3][j];
            float v4 = KVs[64 + tx * 4 + 0][j];
            float v5 = KVs[64 + tx * 4 + 1][j];
            float v6 = KVs[64 + tx * 4 + 2][j];
            float v7 = KVs[64 + tx * 4 + 3][j];
            Oa[0][0] += p0 * v0; Oa[0][1] += p0 * v1; Oa[0][2] += p0 * v2; Oa[0][3] += p0 * v3;
            Oa[0][4] += p0 * v4; Oa[0][5] += p0 * v5; Oa[0][6] += p0 * v6; Oa[0][7] += p0 * v7;
            Oa[1][0] += p1 * v0; Oa[1][1] += p1 * v1; Oa[1][2] += p1 * v2; Oa[1][3] += p1 * v3;
            Oa[1][4] += p1 * v4; Oa[1][5] += p1 * v5; Oa[1][6] += p1 * v6; Oa[1][7] += p1 * v7;
            Oa[2][0] += p2 * v0; Oa[2][1] += p2 * v1; Oa[2][2] += p2 * v2; Oa[2][3] += p2 * v3;
            Oa[2][4] += p2 * v4; Oa[2][5] += p2 * v5; Oa[2][6] += p2 * v6; Oa[2][7] += p2 * v7;
            Oa[3][0] += p3 * v0; Oa[3][1] += p3 * v1; Oa[3][2] += p3 * v2; Oa[3][3] += p3 * v3;
            Oa[3][4] += p3 * v4; Oa[3][5] += p3 * v5; Oa[3][6] += p3 * v6; Oa[3][7] += p3 * v7;
        }
    }

    // epilogue: O / l  -> bf16 (token-major, h*128+d) feeding the O-projection
    unsigned short* obase = O + ((size_t)(b * Ssz + s0)) * (NHsz * Dsz) + h * Dsz;
#pragma unroll
    for (int r = 0; r < 4; r++) {
        float inv = 1.f / l_run[r];
        ushort4 u0, u1;
        u0.x = f2bf(Oa[r][0] * inv); u0.y = f2bf(Oa[r][1] * inv);
        u0.z = f2bf(Oa[r][2] * inv); u0.w = f2bf(Oa[r][3] * inv);
        u1.x = f2bf(Oa[r][4] * inv); u1.y = f2bf(Oa[r][5] * inv);
        u1.z = f2bf(Oa[r][6] * inv); u1.w = f2bf(Oa[r][7] * inv);
        *(ushort4*)(obase + (size_t)(ty * 4 + r) * (NHsz * Dsz) + tx * 4)      = u0;
        *(ushort4*)(obase + (size_t)(ty * 4 + r) * (NHsz * Dsz) + 64 + tx * 4) = u1;
    }
}

// ============================================================================
extern "C" void kernel_launch(void* const* d_in, const int* in_sizes, int n_in,
                              void* d_out, int out_size, void* d_ws, size_t ws_size,
                              hipStream_t stream) {
    (void)in_sizes; (void)n_in; (void)out_size; (void)ws_size;
    const float* hidden    = (const float*)d_in[0];
    const float* k_cache   = (const float*)d_in[1];
    const float* v_cache   = (const float*)d_in[2];
    const float* rope      = (const float*)d_in[3];
    const int*   start_idx = (const int*)d_in[5];
    const float* Wq        = (const float*)d_in[6];
    const float* Wk        = (const float*)d_in[7];
    const float* Wv        = (const float*)d_in[8];
    const float* Wo        = (const float*)d_in[9];
    const float* q_norm_w  = (const float*)d_in[10];
    const float* k_norm_w  = (const float*)d_in[11];

    float* out   = (float*)d_out;
    float* out_k = out + (size_t)Bsz * Ssz * HIDsz;             // 8388608
    float* out_v = out_k + (size_t)Bsz * NKVsz * CAPsz * Dsz;   // +8388608

    // workspace layout (bytes): q_ws f32 32MB | hidden_bf 16MB | attn_bf 16MB |
    // Wq_t 32MB | Wo_t 32MB | Wk_t 8MB | Wv_t 8MB  == 144MB total
    char* ws = (char*)d_ws;
    float*          q_ws      = (float*)ws;                                      // 2048x4096 f32
    unsigned short* hidden_bf = (unsigned short*)(ws + (((size_t) 32) << 20));   // 2048x4096 bf16
    unsigned short* attn_bf   = (unsigned short*)(ws + (((size_t) 48) << 20));   // 2048x4096 bf16
    unsigned short* Wq_t      = (unsigned short*)(ws + (((size_t) 64) << 20));   // 4096x4096 bf16
    unsigned short* Wo_t      = (unsigned short*)(ws + (((size_t) 96) << 20));   // 4096x4096 bf16
    unsigned short* Wk_t      = (unsigned short*)(ws + (((size_t)128) << 20));   // 1024x4096 bf16
    unsigned short* Wv_t      = (unsigned short*)(ws + (((size_t)136) << 20));   // 1024x4096 bf16

    const size_t cache_bytes = (size_t)Bsz * NKVsz * CAPsz * Dsz * sizeof(float);
    (void)hipMemcpyAsync(out_k, k_cache, cache_bytes, hipMemcpyDeviceToDevice, stream);
    (void)hipMemcpyAsync(out_v, v_cache, cache_bytes, hipMemcpyDeviceToDevice, stream);

    // ---- bf16 conversions / weight transposes ----
    convert_bf16_kernel<<<8192, 256, 0, stream>>>(hidden, hidden_bf, 2048 * 4096 / 4);
    transpose_bf16_kernel<<<dim3(64, 64), 256, 0, stream>>>(Wq, Wq_t, HIDsz, NHsz * Dsz);
    transpose_bf16_kernel<<<dim3(16, 64), 256, 0, stream>>>(Wk, Wk_t, HIDsz, NKVsz * Dsz);
    transpose_bf16_kernel<<<dim3(16, 64), 256, 0, stream>>>(Wv, Wv_t, HIDsz, NKVsz * Dsz);
    transpose_bf16_kernel<<<dim3(64, 64), 256, 0, stream>>>(Wo, Wo_t, NHsz * Dsz, HIDsz);

    // ---- QKV projections (MFMA) ----
    gemm_bf16_kernel<0><<<dim3(32, 16), 256, 0, stream>>>(hidden_bf, Wq_t, q_ws, 2048, 4096, 4096, nullptr);
    gemm_bf16_kernel<1><<<dim3(8, 16), 256, 0, stream>>>(hidden_bf, Wk_t, out_k, 2048, 1024, 4096, start_idx);
    gemm_bf16_kernel<1><<<dim3(8, 16), 256, 0, stream>>>(hidden_bf, Wv_t, out_v, 2048, 1024, 4096, start_idx);

    // ---- RMSNorm + RoPE (q in ws; k in-place on cache slice) ----
    rmsnorm_rope_kernel<<<16384, 256, 0, stream>>>(q_ws, q_norm_w, rope, start_idx, NHsz, 0);
    rmsnorm_rope_kernel<<<4096, 256, 0, stream>>>(out_k, k_norm_w, rope, start_idx, NKVsz, 1);

    // ---- Attention (writes bf16) ----
    attn_kernel<<<dim3(8, NHsz, Bsz), 256, 0, stream>>>(q_ws, out_k, out_v, attn_bf, start_idx);

    // ---- Output projection (MFMA) ----
    gemm_bf16_kernel<0><<<dim3(32, 16), 256, 0, stream>>>(attn_bf, Wo_t, out, 2048, 4096, 4096, nullptr);
}

// Round 5
// 842.200 us; speedup vs baseline: 4.3981x; 1.9096x over previous
//
#include <hip/hip_runtime.h>
#include <hip/hip_bf16.h>
#include <cstdint>

#define Bsz   4
#define Ssz   512
#define HIDsz 4096
#define NHsz  32
#define NKVsz 8
#define Dsz   128
#define CAPsz 2048
#define EPSf  1e-6f
#define QK_SCALEf 0.08838834764831845f  // 1/sqrt(128)

typedef __attribute__((ext_vector_type(8))) short short8;
typedef __attribute__((ext_vector_type(4))) float f32x4;

__device__ __forceinline__ unsigned short f2bf(float x) {
    unsigned u = __float_as_uint(x);
    return (unsigned short)((u + 0x7fffu + ((u >> 16) & 1u)) >> 16);
}

// async 16B global->LDS; lds base must be WAVE-UNIFORM (HW adds lane*16)
__device__ __forceinline__ void gload16(const void* g, void* l) {
    __builtin_amdgcn_global_load_lds(
        (const __attribute__((address_space(1))) unsigned int*)g,
        (__attribute__((address_space(3))) unsigned int*)l, 16, 0, 0);
}

// ============================================================================
// f32 -> bf16 flat convert (vectorized float4 -> ushort4)
// ============================================================================
__global__ __launch_bounds__(256) void convert_bf16_kernel(
    const float* __restrict__ in, unsigned short* __restrict__ out, int n4)
{
    int i = blockIdx.x * blockDim.x + threadIdx.x;
    if (i < n4) {
        float4 v = ((const float4*)in)[i];
        ushort4 o;
        o.x = f2bf(v.x); o.y = f2bf(v.y); o.z = f2bf(v.z); o.w = f2bf(v.w);
        ((ushort4*)out)[i] = o;
    }
}

// ============================================================================
// W (K x N, f32 row-major) -> Wt (N x K, bf16 row-major). 64x64 tiles.
// ============================================================================
__global__ __launch_bounds__(256) void transpose_bf16_kernel(
    const float* __restrict__ W, unsigned short* __restrict__ Wt, int K, int N)
{
    __shared__ float tile[64][65];
    const int k0 = blockIdx.y * 64, n0 = blockIdx.x * 64;
    const int t = threadIdx.x;
    const int tr = t >> 4, tc4 = (t & 15) * 4;
#pragma unroll
    for (int i = 0; i < 4; i++) {
        int r = tr + i * 16;
        float4 v = *(const float4*)(W + (size_t)(k0 + r) * N + n0 + tc4);
        tile[r][tc4 + 0] = v.x; tile[r][tc4 + 1] = v.y;
        tile[r][tc4 + 2] = v.z; tile[r][tc4 + 3] = v.w;
    }
    __syncthreads();
#pragma unroll
    for (int i = 0; i < 4; i++) {
        int nr = tr + i * 16;
        ushort4 o;
        o.x = f2bf(tile[tc4 + 0][nr]);
        o.y = f2bf(tile[tc4 + 1][nr]);
        o.z = f2bf(tile[tc4 + 2][nr]);
        o.w = f2bf(tile[tc4 + 3][nr]);
        *(ushort4*)(Wt + (size_t)(n0 + nr) * K + k0 + tc4) = o;
    }
}

// ============================================================================
// V cache (B,NKV,CAP,D f32) -> Vt (B,NKV,D,CAP bf16). 64x64 tiles per (b,kv).
// ============================================================================
__global__ __launch_bounds__(256) void transpose_v_kernel(
    const float* __restrict__ V, unsigned short* __restrict__ Vt)
{
    __shared__ float tile[64][65];   // [cap][d]
    const int c0 = blockIdx.x * 64, d0 = blockIdx.y * 64, bk = blockIdx.z;
    const int t = threadIdx.x;
    const int tr = t >> 4, tc4 = (t & 15) * 4;
    const float* base = V + (size_t)bk * CAPsz * Dsz;
#pragma unroll
    for (int i = 0; i < 4; i++) {
        int r = tr + i * 16;
        float4 v = *(const float4*)(base + (size_t)(c0 + r) * Dsz + d0 + tc4);
        tile[r][tc4 + 0] = v.x; tile[r][tc4 + 1] = v.y;
        tile[r][tc4 + 2] = v.z; tile[r][tc4 + 3] = v.w;
    }
    __syncthreads();
    unsigned short* ob = Vt + (size_t)bk * Dsz * CAPsz;
#pragma unroll
    for (int i = 0; i < 4; i++) {
        int dr = tr + i * 16;
        ushort4 o;
        o.x = f2bf(tile[tc4 + 0][dr]);
        o.y = f2bf(tile[tc4 + 1][dr]);
        o.z = f2bf(tile[tc4 + 2][dr]);
        o.w = f2bf(tile[tc4 + 3][dr]);
        *(ushort4*)(ob + (size_t)(d0 + dr) * CAPsz + c0 + tc4) = o;
    }
}

// ============================================================================
// bf16 MFMA GEMM (m97 structure): C(MxN,f32) = A(MxK,bf16) @ Bt(NxK,bf16)^T
// MODE 0: plain row-major f32 write. MODE 1: scatter into KV cache.
// ============================================================================
template<int MODE>
__global__ __launch_bounds__(256, 2) void gemm_bf16_kernel(
    const unsigned short* __restrict__ A,   // M x K
    const unsigned short* __restrict__ Bt,  // N x K
    float* __restrict__ C, int M, int N, int K,
    const int* __restrict__ start_idx)
{
    __shared__ __align__(16) unsigned short As[128 * 64];
    __shared__ __align__(16) unsigned short Bs[128 * 64];
    const int t    = threadIdx.x;
    const int lane = t & 63, wv = t >> 6;
    const int m0 = blockIdx.y * 128, n0 = blockIdx.x * 128;
    const int rw = (wv & 1) * 64, cw = (wv >> 1) * 64;

    f32x4 acc[4][4];
#pragma unroll
    for (int r = 0; r < 4; r++)
#pragma unroll
        for (int c = 0; c < 4; c++) acc[r][c] = (f32x4){0.f, 0.f, 0.f, 0.f};

    const int arow = lane >> 3;          // 0..7 row within 8-row chunk
    const int acol = (lane & 7) * 8;     // k offset (8 bf16 = 16 B)
    const int fr = lane & 15, fq = (lane >> 4) * 8;

    for (int k0 = 0; k0 < K; k0 += 64) {
        __syncthreads();
#pragma unroll
        for (int i = 0; i < 4; i++) {
            int ro = (i * 4 + wv) * 8;   // 16 chunks x 8 rows = 128 rows
            gload16(A  + (size_t)(m0 + ro + arow) * K + k0 + acol, As + (size_t)ro * 64);
            gload16(Bt + (size_t)(n0 + ro + arow) * K + k0 + acol, Bs + (size_t)ro * 64);
        }
        __syncthreads();
#pragma unroll
        for (int kk = 0; kk < 2; kk++) {
            short8 af[4], bfr[4];
#pragma unroll
            for (int r = 0; r < 4; r++)
                af[r] = *(const short8*)&As[(rw + r * 16 + fr) * 64 + kk * 32 + fq];
#pragma unroll
            for (int c = 0; c < 4; c++)
                bfr[c] = *(const short8*)&Bs[(cw + c * 16 + fr) * 64 + kk * 32 + fq];
#pragma unroll
            for (int r = 0; r < 4; r++)
#pragma unroll
                for (int c = 0; c < 4; c++)
                    acc[r][c] = __builtin_amdgcn_mfma_f32_16x16x32_bf16(
                        af[r], bfr[c], acc[r][c], 0, 0, 0);
        }
    }

    int pos0 = 0;
    if (MODE == 1) pos0 = start_idx[m0 >> 9];
#pragma unroll
    for (int r = 0; r < 4; r++) {
#pragma unroll
        for (int c = 0; c < 4; c++) {
            int col = n0 + cw + c * 16 + (lane & 15);
#pragma unroll
            for (int reg = 0; reg < 4; reg++) {
                int row = m0 + rw + r * 16 + (lane >> 4) * 4 + reg;
                float val = acc[r][c][reg];
                if (MODE == 0) {
                    C[(size_t)row * N + col] = val;
                } else {
                    int pos = pos0 + (row & (Ssz - 1));
                    int kvh = col >> 7, d = col & 127;
                    int b = row >> 9;
                    C[((size_t)(b * NKVsz + kvh) * CAPsz + pos) * Dsz + d] = val;
                }
            }
        }
    }
}

// ============================================================================
// RMSNorm + RoPE, one wave per (token, head) row of 128.
// mode 0: read X f32 (2048, nheads*128), write Xbf bf16 scaled by QK_SCALE
// mode 1: in-place f32 on (B, nheads, CAP, D) cache at row pos=start+s
// ============================================================================
__global__ __launch_bounds__(256) void rmsnorm_rope_kernel(
    float* __restrict__ X, unsigned short* __restrict__ Xbf,
    const float* __restrict__ w,
    const float* __restrict__ rope, const int* __restrict__ start_idx,
    int nheads, int mode)
{
    int gid   = blockIdx.x * blockDim.x + threadIdx.x;
    int wid   = gid >> 6;
    int lane  = threadIdx.x & 63;
    int token = wid / nheads;
    int h     = wid - token * nheads;
    int b = token >> 9, s = token & (Ssz - 1);
    int pos = start_idx[b] + s;
    float* row;
    if (mode == 0) row = X + (size_t)token * (nheads * Dsz) + h * Dsz;
    else           row = X + ((size_t)(b * nheads + h) * CAPsz + pos) * Dsz;

    float x1 = row[lane], x2 = row[lane + 64];
    float ss = x1 * x1 + x2 * x2;
#pragma unroll
    for (int off = 32; off > 0; off >>= 1) ss += __shfl_xor(ss, off);
    float rn  = rsqrtf(ss * (1.f / 128.f) + EPSf);
    float xn1 = x1 * rn * w[lane];
    float xn2 = x2 * rn * w[lane + 64];
    float c   = rope[(size_t)pos * Dsz + lane];        // cos
    float sn  = rope[(size_t)pos * Dsz + 64 + lane];   // sin
    float o1 = xn1 * c - xn2 * sn;
    float o2 = xn2 * c + xn1 * sn;
    if (mode == 0) {
        unsigned short* orow = Xbf + (size_t)token * (nheads * Dsz) + h * Dsz;
        orow[lane]      = f2bf(o1 * QK_SCALEf);
        orow[lane + 64] = f2bf(o2 * QK_SCALEf);
    } else {
        row[lane]      = o1;
        row[lane + 64] = o2;
    }
}

// ============================================================================
// MFMA flash attention. Block = (32 q-rows, kv-group, batch), 4 waves = the
// 4 GQA heads sharing one K/V LDS tile. K tile [key][d], V^T tile [d][key],
// both gload16-staged bf16. Q a-frags register-resident (pre-scaled bf16).
// Online softmax on C-layout frags; P -> padded LDS -> A-frags for PV.
// ============================================================================
__global__ __launch_bounds__(256, 2) void attn_mfma_kernel(
    const unsigned short* __restrict__ Qbf,   // [B][S][NH*D]
    const unsigned short* __restrict__ Kbf,   // [B][NKV][CAP][D]
    const unsigned short* __restrict__ Vtbf,  // [B][NKV][D][CAP]
    unsigned short* __restrict__ O,           // [B][S][NH*D]
    const int* __restrict__ start_idx)
{
    __shared__ __align__(16) unsigned short Ks[64 * 128];     // [key][d]
    __shared__ __align__(16) unsigned short Vs[128 * 64];     // [d][key]
    __shared__ __align__(16) unsigned short Ps[4][32 * 72];   // per-wave [row][key], pad 72

    const int t = threadIdx.x, lane = t & 63, wv = t >> 6;
    const int l15 = lane & 15, l4 = lane >> 4;
    const int qt = blockIdx.x, kv = blockIdx.y, b = blockIdx.z;
    const int h = kv * 4 + wv;
    const int s0 = qt * 32;
    const int start = start_idx[b];

    // Q a-frags: A[m=l15][k=l4*8+j], 2 m-tiles x 4 k-tiles (d=128)
    short8 aq[2][4];
    const unsigned short* qb = Qbf + ((size_t)(b * Ssz + s0)) * HIDsz + h * Dsz;
#pragma unroll
    for (int m2 = 0; m2 < 2; m2++)
#pragma unroll
        for (int kq = 0; kq < 4; kq++)
            aq[m2][kq] = *(const short8*)(qb + (size_t)(m2 * 16 + l15) * HIDsz + kq * 32 + l4 * 8);

    f32x4 Oacc[2][8];
    float m_run[2][4], l_run[2][4];
#pragma unroll
    for (int m2 = 0; m2 < 2; m2++) {
#pragma unroll
        for (int nd = 0; nd < 8; nd++) Oacc[m2][nd] = (f32x4){0.f, 0.f, 0.f, 0.f};
#pragma unroll
        for (int r = 0; r < 4; r++) { m_run[m2][r] = -1e30f; l_run[m2][r] = 0.f; }
    }

    const unsigned short* kb = Kbf + (size_t)(b * NKVsz + kv) * CAPsz * Dsz;
    const unsigned short* vb = Vtbf + (size_t)(b * NKVsz + kv) * (size_t)Dsz * CAPsz;

    int t_hi = start + s0 + 31;
    if (t_hi > CAPsz - 1) t_hi = CAPsz - 1;

    for (int t0 = 0; t0 <= t_hi; t0 += 64) {
        __syncthreads();                       // prev frag reads done
        // stage K tile: 64 rows x 256B; one gload16 = 4 rows; 4 per wave
#pragma unroll
        for (int i = 0; i < 4; i++) {
            int ro = (i * 4 + wv) * 4;
            gload16(kb + (size_t)(t0 + ro + l4) * Dsz + l15 * 8, Ks + ro * 128);
        }
        // stage V^T tile: 128 rows x 128B; one gload16 = 8 rows; 4 per wave
#pragma unroll
        for (int i = 0; i < 4; i++) {
            int ro = (i * 4 + wv) * 8;
            gload16(vb + (size_t)(ro + (lane >> 3)) * CAPsz + t0 + (lane & 7) * 8,
                    Vs + ro * 64);
        }
        __syncthreads();

        // ---- S = Q @ K^T  (C layout: col=key=n*16+l15, row=m2*16+l4*4+reg)
        f32x4 Sacc[2][4];
#pragma unroll
        for (int m2 = 0; m2 < 2; m2++)
#pragma unroll
            for (int n = 0; n < 4; n++) Sacc[m2][n] = (f32x4){0.f, 0.f, 0.f, 0.f};
#pragma unroll
        for (int kq = 0; kq < 4; kq++) {
            short8 bk[4];
#pragma unroll
            for (int n = 0; n < 4; n++)
                bk[n] = *(const short8*)&Ks[(n * 16 + l15) * 128 + kq * 32 + l4 * 8];
#pragma unroll
            for (int m2 = 0; m2 < 2; m2++)
#pragma unroll
                for (int n = 0; n < 4; n++)
                    Sacc[m2][n] = __builtin_amdgcn_mfma_f32_16x16x32_bf16(
                        aq[m2][kq], bk[n], Sacc[m2][n], 0, 0, 0);
        }

        // ---- online softmax on fragments
        bool need_mask = (t0 + 63) > (start + s0);
#pragma unroll
        for (int m2 = 0; m2 < 2; m2++) {
#pragma unroll
            for (int reg = 0; reg < 4; reg++) {
                int rloc = m2 * 16 + l4 * 4 + reg;
                int row_pos = start + s0 + rloc;
                float sv[4];
#pragma unroll
                for (int n = 0; n < 4; n++) {
                    sv[n] = Sacc[m2][n][reg];
                    if (need_mask && (t0 + n * 16 + l15 > row_pos)) sv[n] = -1e30f;
                }
                float mrow = fmaxf(fmaxf(sv[0], sv[1]), fmaxf(sv[2], sv[3]));
#pragma unroll
                for (int off = 1; off < 16; off <<= 1)
                    mrow = fmaxf(mrow, __shfl_xor(mrow, off));
                float m_new = fmaxf(m_run[m2][reg], mrow);
                float alpha = __expf(m_run[m2][reg] - m_new);
                float ps = 0.f;
#pragma unroll
                for (int n = 0; n < 4; n++) {
                    sv[n] = __expf(sv[n] - m_new);
                    ps += sv[n];
                }
#pragma unroll
                for (int off = 1; off < 16; off <<= 1)
                    ps += __shfl_xor(ps, off);
                l_run[m2][reg] = l_run[m2][reg] * alpha + ps;
                m_run[m2][reg] = m_new;
#pragma unroll
                for (int nd = 0; nd < 8; nd++) Oacc[m2][nd][reg] *= alpha;
#pragma unroll
                for (int n = 0; n < 4; n++)
                    Ps[wv][rloc * 72 + n * 16 + l15] = f2bf(sv[n]);
            }
        }
        // (no barrier: each wave reads only its own Ps slice; lgkmcnt orders it)

        // ---- O += P @ V   (A = Ps[m=l15][k], B = Vs[n=d][k=key])
#pragma unroll
        for (int kp = 0; kp < 2; kp++) {
            short8 ap[2];
#pragma unroll
            for (int m2 = 0; m2 < 2; m2++)
                ap[m2] = *(const short8*)&Ps[wv][(m2 * 16 + l15) * 72 + kp * 32 + l4 * 8];
#pragma unroll
            for (int nd = 0; nd < 8; nd++) {
                short8 bv = *(const short8*)&Vs[(nd * 16 + l15) * 64 + kp * 32 + l4 * 8];
#pragma unroll
                for (int m2 = 0; m2 < 2; m2++)
                    Oacc[m2][nd] = __builtin_amdgcn_mfma_f32_16x16x32_bf16(
                        ap[m2], bv, Oacc[m2][nd], 0, 0, 0);
            }
        }
    }

    // ---- epilogue: O/l -> bf16 token-major
    unsigned short* ob = O + ((size_t)(b * Ssz + s0)) * HIDsz + h * Dsz;
#pragma unroll
    for (int m2 = 0; m2 < 2; m2++)
#pragma unroll
        for (int reg = 0; reg < 4; reg++) {
            int rloc = m2 * 16 + l4 * 4 + reg;
            float inv = 1.f / l_run[m2][reg];
#pragma unroll
            for (int nd = 0; nd < 8; nd++)
                ob[(size_t)rloc * HIDsz + nd * 16 + l15] = f2bf(Oacc[m2][nd][reg] * inv);
        }
}

// ============================================================================
extern "C" void kernel_launch(void* const* d_in, const int* in_sizes, int n_in,
                              void* d_out, int out_size, void* d_ws, size_t ws_size,
                              hipStream_t stream) {
    (void)in_sizes; (void)n_in; (void)out_size; (void)ws_size;
    const float* hidden    = (const float*)d_in[0];
    const float* k_cache   = (const float*)d_in[1];
    const float* v_cache   = (const float*)d_in[2];
    const float* rope      = (const float*)d_in[3];
    const int*   start_idx = (const int*)d_in[5];
    const float* Wq        = (const float*)d_in[6];
    const float* Wk        = (const float*)d_in[7];
    const float* Wv        = (const float*)d_in[8];
    const float* Wo        = (const float*)d_in[9];
    const float* q_norm_w  = (const float*)d_in[10];
    const float* k_norm_w  = (const float*)d_in[11];

    float* out   = (float*)d_out;
    float* out_k = out + (size_t)Bsz * Ssz * HIDsz;
    float* out_v = out_k + (size_t)Bsz * NKVsz * CAPsz * Dsz;

    // workspace (MB): [0,32) q_ws f32, later reused as Kbf [0,16) + Vtbf [16,32)
    //                 (q_ws dead after rmsnorm-q; Kbf/Vtbf written after)
    // [32,48) hidden_bf | [48,64) attn_bf | [64,80) qbf | [80,112) Wqo_t (Wq then Wo)
    // [112,120) Wk_t | [120,128) Wv_t   == 128 MB total (prev round used 144 OK)
    char* ws = (char*)d_ws;
    float*          q_ws      = (float*)ws;
    unsigned short* Kbf       = (unsigned short*)ws;
    unsigned short* Vtbf      = (unsigned short*)(ws + (((size_t) 16) << 20));
    unsigned short* hidden_bf = (unsigned short*)(ws + (((size_t) 32) << 20));
    unsigned short* attn_bf   = (unsigned short*)(ws + (((size_t) 48) << 20));
    unsigned short* qbf       = (unsigned short*)(ws + (((size_t) 64) << 20));
    unsigned short* Wqo_t     = (unsigned short*)(ws + (((size_t) 80) << 20));
    unsigned short* Wk_t      = (unsigned short*)(ws + (((size_t)112) << 20));
    unsigned short* Wv_t      = (unsigned short*)(ws + (((size_t)120) << 20));

    const size_t cache_bytes = (size_t)Bsz * NKVsz * CAPsz * Dsz * sizeof(float);
    (void)hipMemcpyAsync(out_k, k_cache, cache_bytes, hipMemcpyDeviceToDevice, stream);
    (void)hipMemcpyAsync(out_v, v_cache, cache_bytes, hipMemcpyDeviceToDevice, stream);

    // bf16 conversions / weight transposes
    convert_bf16_kernel<<<8192, 256, 0, stream>>>(hidden, hidden_bf, 2048 * 4096 / 4);
    transpose_bf16_kernel<<<dim3(64, 64), 256, 0, stream>>>(Wq, Wqo_t, HIDsz, NHsz * Dsz);
    transpose_bf16_kernel<<<dim3(16, 64), 256, 0, stream>>>(Wk, Wk_t, HIDsz, NKVsz * Dsz);
    transpose_bf16_kernel<<<dim3(16, 64), 256, 0, stream>>>(Wv, Wv_t, HIDsz, NKVsz * Dsz);

    // QKV projections (MFMA)
    gemm_bf16_kernel<0><<<dim3(32, 16), 256, 0, stream>>>(hidden_bf, Wqo_t, q_ws, 2048, 4096, 4096, nullptr);
    gemm_bf16_kernel<1><<<dim3(8, 16), 256, 0, stream>>>(hidden_bf, Wk_t, out_k, 2048, 1024, 4096, start_idx);
    gemm_bf16_kernel<1><<<dim3(8, 16), 256, 0, stream>>>(hidden_bf, Wv_t, out_v, 2048, 1024, 4096, start_idx);

    // RMSNorm + RoPE: q -> qbf (bf16, pre-scaled); k in-place on cache slice
    rmsnorm_rope_kernel<<<16384, 256, 0, stream>>>(q_ws, qbf, q_norm_w, rope, start_idx, NHsz, 0);
    rmsnorm_rope_kernel<<<4096, 256, 0, stream>>>(out_k, nullptr, k_norm_w, rope, start_idx, NKVsz, 1);

    // K cache -> bf16 (same layout); V cache -> bf16 transposed [d][cap]
    // (q_ws is dead now; Kbf/Vtbf overwrite it)
    convert_bf16_kernel<<<8192, 256, 0, stream>>>(out_k, Kbf, Bsz * NKVsz * CAPsz * Dsz / 4);
    transpose_v_kernel<<<dim3(32, 2, 32), 256, 0, stream>>>(out_v, Vtbf);

    // MFMA flash attention (writes bf16 token-major)
    attn_mfma_kernel<<<dim3(16, NKVsz, Bsz), 256, 0, stream>>>(qbf, Kbf, Vtbf, attn_bf, start_idx);

    // Wo transpose (Wqo_t free after Q-proj), then output projection
    transpose_bf16_kernel<<<dim3(64, 64), 256, 0, stream>>>(Wo, Wqo_t, NHsz * Dsz, HIDsz);
    gemm_bf16_kernel<0><<<dim3(32, 16), 256, 0, stream>>>(attn_bf, Wqo_t, out, 2048, 4096, 4096, nullptr);
}